// Round 15
// baseline (258.179 us; speedup 1.0000x reference)
//
#include <hip/hip_runtime.h>

// ---------------- problem constants ----------------
#define B_DIM   8
#define NPTS    81920
#define DTOT    20          // DL(16) + DA(4)
#define DT_STEP 0.1f

// ---------------- kernel geometry ----------------
#define BLOCK 512           // 8 waves share one LDS weight image
#define GRID  1280          // r13-verified best: (GRID/8)*ITERS*128 = 81920
#define ITERS 4
#define PPI   128           // points per iter per block (8 waves x 16)
#define NFRAG 21
#define FIMG_BYTES 32768
#define LDS_W_BYTES 16384   // B1f ONLY (16 KB exactly) — W2f back in regs.
                            // Theory: LDS wg-alloc pool ~64KB/CU -> 20.5KB
                            // image capped us at 3 blocks/CU; 16KB -> 4.
#define TANH_SCALE 2.885390082f   // 2*log2(e), folded into baked W1/b1

// split mirror: DL rows 32B (ping-pong, THE inter-step state), DA rows 8B
// (static, written once)
#define MDL_ROW 32
#define MDA_ROW 8

typedef __attribute__((ext_vector_type(8))) short    short8;   // 8 bf16
typedef __attribute__((ext_vector_type(4))) float    f32x4;
typedef __attribute__((ext_vector_type(2))) unsigned u32x2;
typedef __attribute__((ext_vector_type(4))) unsigned u32x4;
typedef __attribute__((ext_vector_type(2))) short    short2v;

__device__ __forceinline__ unsigned short f2bf(float f) {
    unsigned u = __builtin_bit_cast(unsigned, f);
    u += 0x7FFFu + ((u >> 16) & 1u);           // RNE
    return (unsigned short)(u >> 16);
}
#if __has_builtin(__builtin_amdgcn_cvt_pk_bf16_f32)
__device__ __forceinline__ unsigned pack2(float a, float b) {
    short2v p = __builtin_amdgcn_cvt_pk_bf16_f32(a, b);
    return __builtin_bit_cast(unsigned, p);
}
#else
__device__ __forceinline__ unsigned pack2(float a, float b) {
    return (unsigned)f2bf(a) | ((unsigned)f2bf(b) << 16);
}
#endif
// unpack 4 bf16 (u32x2) -> f32x4, exact
__device__ __forceinline__ f32x4 unpack4(u32x2 m) {
    f32x4 o;
    o.x = __builtin_bit_cast(float, m.x << 16);
    o.y = __builtin_bit_cast(float, m.x & 0xffff0000u);
    o.z = __builtin_bit_cast(float, m.y << 16);
    o.w = __builtin_bit_cast(float, m.y & 0xffff0000u);
    return o;
}
// tanh with the 2*log2(e) scale pre-folded into W1/b1:
// tanh(x) = 1 - 2/(exp2(a)+1) where a = x*2*log2e comes out of the MFMA.
__device__ __forceinline__ float tanh_folded(float a) {
    float e = __builtin_amdgcn_exp2f(a);
    float r = __builtin_amdgcn_rcpf(1.0f + e);
    return 1.0f - 2.0f * r;
}

// L1 k-slot (ks,q,j) -> feature index (0..59), 60 = bias, 61 = zero pad.
// (Hardware-verified correct in rounds 2-14.)
__device__ __forceinline__ int feat_of(int ks, int q, int j) {
    if (ks == 0) {
        if (q == 0) return j;                       // r0 DL 0-7
        if (q == 1) return 8 + j;                   // r0 DL 8-15
        if (q == 2) return 20 + j;                  // r1 DL 0-7
        return (j < 4) ? 16 + j : 36 + (j - 4);     // r0 DA | r1 DA
    }
    if (q == 0) return 28 + j;                      // r1 DL 8-15
    if (q == 1) return 40 + j;                      // r2 DL 0-7
    if (q == 2) return 48 + j;                      // r2 DL 8-15
    if (j < 4) return 56 + j;                       // r2 DA
    return (j == 4) ? 60 : 61;                      // bias | zero
}

// L2 k-slot (ks,q,j) -> hidden index (sigma bake; verified r9-r14).
__device__ __forceinline__ int hid_of(int ks, int q, int j) {
    return (2 * ks + (j >> 2)) * 16 + q * 4 + (j & 3);
}

// ---- dispatch 1: split bf16 mirror build + fragment bake (verified r10-r14) ----
__global__ __launch_bounds__(256) void build_mirror(
    const f32x4* __restrict__ in, char* __restrict__ m0dl,
    char* __restrict__ mda, f32x4* __restrict__ outF, int n4,
    const float* __restrict__ W1, const float* __restrict__ b1,
    const float* __restrict__ W2, const float* __restrict__ b2,
    char* __restrict__ img)
{
    const int i = blockIdx.x * 256 + threadIdx.x;
    if (i < n4) {
        f32x4 v = in[i];
        u32x2 o; o.x = pack2(v.x, v.y); o.y = pack2(v.z, v.w);
        const int r = i / 5, c = i % 5;          // row, f32x4-within-row
        if (c < 4) {                             // DL piece -> 32B-row mirror
            *(u32x2*)(m0dl + (size_t)r * MDL_ROW + c * 8) = o;
        } else {                                 // DA piece -> static mirror
            *(u32x2*)(mda + (size_t)r * MDA_ROW) = o;
            outF[i] = v;                         // constant DA of output
        }
    }
    if (blockIdx.x == 0) {           // fragment bake (tiny, uniform branch)
        const int t = threadIdx.x, lane = t & 63, g = t >> 6;
        const int l15 = lane & 15, q = lane >> 4;
        for (int f = g; f < NFRAG; f += 4) {
            char* dst = img + (f * 64 + lane) * 16;
            if (f < 16) {                       // B1f[nt][ks]: A[m=nt*16+l15][k]
                const int nt = f >> 1, ks = f & 1, m = nt * 16 + l15;
                unsigned short v[8];
                #pragma unroll
                for (int j = 0; j < 8; j++) {
                    const int ft = feat_of(ks, q, j);
                    float x = (ft < 60) ? TANH_SCALE * W1[ft * 128 + m]
                                        : (ft == 60 ? TANH_SCALE * b1[m] : 0.0f);
                    v[j] = f2bf(x);
                }
                *(u32x4*)dst = *(const u32x4*)v;
            } else if (f < 20) {                // W2f[ks]: sigma-permuted, DT-scaled
                const int ks = f - 16;
                unsigned short v[8];
                #pragma unroll
                for (int j = 0; j < 8; j++) {
                    const int H = hid_of(ks, q, j);
                    v[j] = f2bf(DT_STEP * W2[H * 16 + l15]);
                }
                *(u32x4*)dst = *(const u32x4*)v;
            } else {                            // acc2init: DT*b2[q*4+r]
                f32x4 a = { DT_STEP * b2[q * 4 + 0], DT_STEP * b2[q * 4 + 1],
                            DT_STEP * b2[q * 4 + 2], DT_STEP * b2[q * 4 + 3] };
                *(f32x4*)dst = a;
            }
        }
    }
}

// split-mirror gather with DEDUPED indices: each lane receives only the 2
// (q3: 3) row indices it actually uses. q3's 16B loads over-read 8B past
// the DA row; Mda is followed by the frag image -> in-bounds, discarded.
__device__ __forceinline__ void gather3(
    const char* __restrict__ MdlB, const char* __restrict__ MdaB,
    int ixA, int ixB, int ixC, int offA, int offB, bool q3,
    u32x4& A, u32x4& Bv, u32x2& C)
{
    const char* aA = q3 ? (MdaB + (size_t)ixA * MDA_ROW)
                        : (MdlB + (size_t)ixA * MDL_ROW + offA);
    const char* aB = q3 ? (MdaB + (size_t)ixB * MDA_ROW)
                        : (MdlB + (size_t)ixB * MDL_ROW + offB);
    A  = *(const u32x4*)aA;
    Bv = *(const u32x4*)aB;
    u32x2 c = { 0u, 0u };
    if (q3) c = *(const u32x2*)(MdaB + (size_t)ixC * MDA_ROW);
    C = c;
}

// ---- one Euler step. r13 geometry (best: 41.1 us/step), LDS image cut to
// 16KB (W2f back in registers) to test the 64KB/CU LDS-allocation-pool
// theory: 20.5KB capped at 3 blocks/CU; 16KB should admit 4. nbr loads
// deduped: 2 per lane (q3: +1 predicated) via per-q index offsets. ----
__global__ __launch_bounds__(BLOCK) void neural_step(
    float* __restrict__ Yout,
    const char* __restrict__ Mdl_in, char* __restrict__ Mdl_out,
    const char* __restrict__ Mda,
    const int* __restrict__ nbr, const char* __restrict__ img,
    const int last)
{
    __shared__ __align__(16) char sW[LDS_W_BYTES];   // B1f frags 0..15 only
    const int t = threadIdx.x, lane = t & 63, w = t >> 6;
    const int l15 = lane & 15, q = lane >> 4;
    const bool q3 = (q == 3);
    // deduped nbr slots: rowA = nbr[ofsA], rowB = nbr[ofsB] (q3: +nbr[2])
    const int ofsA = (q == 2) ? 1 : 0;                  // q: [0,0,1,0]
    const int ofsB = (q == 0 || q3) ? 1 : 2;            // q: [1,2,2,1]
    const int offA = (q == 1) ? 16 : 0;                 // within 32B DL row
    const int offB = (q == 0) || (q == 2) ? 16 : 0;

    const int bk = blockIdx.x;
    const int bB = bk & 7;                 // batch <-> XCD (perf heuristic only)
    const int p0 = (bk >> 3) * (ITERS * PPI) + w * 16 + l15;
    const size_t rowBase = (size_t)bB * NPTS;
    const char* MdlB = Mdl_in  + (size_t)bB * NPTS * MDL_ROW;
    char*       MdoB = Mdl_out + (size_t)bB * NPTS * MDL_ROW;
    const char* MdaB = Mda     + (size_t)bB * NPTS * MDA_ROW;

    // ---- prologue VMEM first: nbr(0,1), gather(0), own(0) in flight ----
    int ixA, ixB, ixC = 0, iyA = 0, iyB = 0, iyC = 0;
    u32x4 gA, gB, nA = {0,0,0,0}, nB = {0,0,0,0};
    u32x2 gC, nC = {0,0};
    u32x2 ownC, ownN = {0u, 0u};
    {
        const int* np = nbr + (size_t)p0 * 3;
        int a = np[ofsA], b = np[ofsB], c = 0;
        if (q3) c = np[2];
        gather3(MdlB, MdaB, a, b, c, offA, offB, q3, gA, gB, gC);
        ownC = *(const u32x2*)(MdlB + (size_t)p0 * MDL_ROW + q * 8);
        const int* np1 = nbr + (size_t)(p0 + PPI) * 3;
        ixA = np1[ofsA]; ixB = np1[ofsB];
        if (q3) ixC = np1[2];
    }

    // ---- stage B1f into LDS (16KB exactly; 512 thr x 2 x 16B) ----
    {
        const u32x4* src = (const u32x4*)img;        // frags 0..15 = 16 KB
        u32x4* dst = (u32x4*)sW;
        dst[t]       = src[t];
        dst[t + 512] = src[t + 512];
    }
    // W2f + acc2init in registers (16+4 VGPR; L2-resident broadcast loads)
    const short8* frg = (const short8*)img;
    short8 W2f[4];
    #pragma unroll
    for (int ks = 0; ks < 4; ks++)
        W2f[ks] = frg[(16 + ks) * 64 + lane];
    const f32x4 acc2init = ((const f32x4*)img)[20 * 64 + lane];
    __syncthreads();

    const char* sWl = sW + lane * 16;                // per-lane fragment base

    #pragma unroll
    for (int it = 0; it < ITERS; it++) {
        // ---- prefetch next iter's own row + gather; it+2's nbr ----
        if (it + 1 < ITERS) {
            ownN = *(const u32x2*)(MdlB + (size_t)(p0 + (it + 1) * PPI) * MDL_ROW
                                   + q * 8);
            gather3(MdlB, MdaB, ixA, ixB, ixC, offA, offB, q3, nA, nB, nC);
        }
        if (it + 2 < ITERS) {
            const int* np = nbr + (size_t)(p0 + (it + 2) * PPI) * 3;
            iyA = np[ofsA]; iyB = np[ofsB];
            if (q3) iyC = np[2];
        }

        // assemble permuted B-fragments (q<3: A|B straight; q3: DA pieces +
        // folded bias {1,0,0,0})
        u32x4 u0 = { gA.x, gA.y, q3 ? gB.x : gA.z, q3 ? gB.y : gA.w };
        u32x4 u1 = { q3 ? gC.x : gB.x, q3 ? gC.y : gB.y,
                     q3 ? 0x00003F80u : gB.z, q3 ? 0u : gB.w };
        short8 zb0 = __builtin_bit_cast(short8, u0);
        short8 zb1 = __builtin_bit_cast(short8, u1);

        // ---- layer 1: h in registers; A-operands streamed from LDS ----
        unsigned hx[8], hy[8];
        #pragma unroll
        for (int nt = 0; nt < 8; nt++) {
            short8 a0 = *(const short8*)(sWl + (nt * 2 + 0) * 1024);
            short8 a1 = *(const short8*)(sWl + (nt * 2 + 1) * 1024);
            f32x4 acc = { 0.f, 0.f, 0.f, 0.f };
            acc = __builtin_amdgcn_mfma_f32_16x16x32_bf16(a0, zb0, acc, 0, 0, 0);
            acc = __builtin_amdgcn_mfma_f32_16x16x32_bf16(a1, zb1, acc, 0, 0, 0);
            hx[nt] = pack2(tanh_folded(acc[0]), tanh_folded(acc[1]));
            hy[nt] = pack2(tanh_folded(acc[2]), tanh_folded(acc[3]));
        }

        // ---- layer 2: A from registers (W2f), B direct from h (sigma bake) ----
        f32x4 acc2 = acc2init;
        #pragma unroll
        for (int ks = 0; ks < 4; ks++) {
            u32x4 hu = { hx[2 * ks], hy[2 * ks], hx[2 * ks + 1], hy[2 * ks + 1] };
            acc2 = __builtin_amdgcn_mfma_f32_16x16x32_bf16(
                W2f[ks], __builtin_bit_cast(short8, hu), acc2, 0, 0, 0);
        }

        // ---- epilogue: fp32 update of the lane's 4 DL channels ----
        f32x4 o = unpack4(ownC);
        o.x += acc2[0]; o.y += acc2[1]; o.z += acc2[2]; o.w += acc2[3];
        if (!last) {
            char* mrow = MdoB + (size_t)(p0 + it * PPI) * MDL_ROW;
            u32x2 mw; mw.x = pack2(o.x, o.y); mw.y = pack2(o.z, o.w);
            *(u32x2*)(mrow + q * 8) = mw;
        } else {
            const size_t row = rowBase + (size_t)(p0 + it * PPI);
            __builtin_nontemporal_store(o, (f32x4*)(Yout + row * DTOT) + q);
        }

        // rotate pipeline
        ownC = ownN;
        gA = nA; gB = nB; gC = nC;
        ixA = iyA; ixB = iyB; ixC = iyC;
    }
}

extern "C" void kernel_launch(void* const* d_in, const int* in_sizes, int n_in,
                              void* d_out, int out_size, void* d_ws, size_t ws_size,
                              hipStream_t stream) {
    const float* inputs = (const float*)d_in[0];
    const int*   nbr    = (const int*)  d_in[1];
    const float* W1     = (const float*)d_in[2];
    const float* b1     = (const float*)d_in[3];
    const float* W2     = (const float*)d_in[4];
    const float* b2     = (const float*)d_in[5];
    float* out = (float*)d_out;

    const size_t MDL_BYTES = (size_t)B_DIM * NPTS * MDL_ROW;  // 21.0 MB each
    const size_t MDA_BYTES = (size_t)B_DIM * NPTS * MDA_ROW;  // 5.24 MB
    char* M0 = (char*)d_ws;
    char* M1 = (char*)d_ws + MDL_BYTES;
    char* DA = (char*)d_ws + 2 * MDL_BYTES;
    char* FI = DA + MDA_BYTES;              // frag image (follows DA: q3
                                            // 8B over-reads land here)

    const int n4 = B_DIM * NPTS * DTOT / 4;                 // 3,276,800
    build_mirror<<<n4 / 256, 256, 0, stream>>>(
        (const f32x4*)inputs, M0, DA, (f32x4*)out, n4,
        W1, b1, W2, b2, FI);

    const dim3 grid(GRID), block(BLOCK);
    neural_step<<<grid, block, 0, stream>>>(out, M0, M1, DA, nbr, FI, 0);
    neural_step<<<grid, block, 0, stream>>>(out, M1, M0, DA, nbr, FI, 0);
    neural_step<<<grid, block, 0, stream>>>(out, M0, M1, DA, nbr, FI, 0);
    neural_step<<<grid, block, 0, stream>>>(out, M1, M0, DA, nbr, FI, 1);
}

// Round 16
// 248.102 us; speedup vs baseline: 1.0406x; 1.0406x over previous
//
#include <hip/hip_runtime.h>

// ---------------- problem constants ----------------
#define B_DIM   8
#define NPTS    81920
#define DTOT    20          // DL(16) + DA(4)
#define DT_STEP 0.1f

// ---------------- kernel geometry ----------------
#define BLOCK 512           // 8 waves share one LDS weight image
#define GRID  1280          // r13-verified best: (GRID/8)*ITERS*128 = 81920
#define ITERS 4
#define PPI   128           // points per iter per block (8 waves x 16)
#define NFRAG 21
#define FIMG_BYTES 32768
#define LDS_W_BYTES 20480   // B1f (16 KB) + W2f (4 KB) in LDS
#define TANH_SCALE 2.885390082f   // 2*log2(e), folded into baked W1/b1

// split mirror: DL rows 32B (ping-pong, THE inter-step state), DA rows 8B
// (static, written once)
#define MDL_ROW 32
#define MDA_ROW 8

typedef __attribute__((ext_vector_type(8))) short    short8;   // 8 bf16
typedef __attribute__((ext_vector_type(4))) float    f32x4;
typedef __attribute__((ext_vector_type(2))) unsigned u32x2;
typedef __attribute__((ext_vector_type(4))) unsigned u32x4;
typedef __attribute__((ext_vector_type(2))) short    short2v;

__device__ __forceinline__ unsigned short f2bf(float f) {
    unsigned u = __builtin_bit_cast(unsigned, f);
    u += 0x7FFFu + ((u >> 16) & 1u);           // RNE
    return (unsigned short)(u >> 16);
}
#if __has_builtin(__builtin_amdgcn_cvt_pk_bf16_f32)
__device__ __forceinline__ unsigned pack2(float a, float b) {
    short2v p = __builtin_amdgcn_cvt_pk_bf16_f32(a, b);
    return __builtin_bit_cast(unsigned, p);
}
#else
__device__ __forceinline__ unsigned pack2(float a, float b) {
    return (unsigned)f2bf(a) | ((unsigned)f2bf(b) << 16);
}
#endif
// unpack 4 bf16 (u32x2) -> f32x4, exact
__device__ __forceinline__ f32x4 unpack4(u32x2 m) {
    f32x4 o;
    o.x = __builtin_bit_cast(float, m.x << 16);
    o.y = __builtin_bit_cast(float, m.x & 0xffff0000u);
    o.z = __builtin_bit_cast(float, m.y << 16);
    o.w = __builtin_bit_cast(float, m.y & 0xffff0000u);
    return o;
}
// tanh with the 2*log2(e) scale pre-folded into W1/b1:
// tanh(x) = 1 - 2/(exp2(a)+1) where a = x*2*log2e comes out of the MFMA.
__device__ __forceinline__ float tanh_folded(float a) {
    float e = __builtin_amdgcn_exp2f(a);
    float r = __builtin_amdgcn_rcpf(1.0f + e);
    return 1.0f - 2.0f * r;
}

// L1 k-slot (ks,q,j) -> feature index (0..59), 60 = bias, 61 = zero pad.
// (Hardware-verified correct in rounds 2-15.)
__device__ __forceinline__ int feat_of(int ks, int q, int j) {
    if (ks == 0) {
        if (q == 0) return j;                       // r0 DL 0-7
        if (q == 1) return 8 + j;                   // r0 DL 8-15
        if (q == 2) return 20 + j;                  // r1 DL 0-7
        return (j < 4) ? 16 + j : 36 + (j - 4);     // r0 DA | r1 DA
    }
    if (q == 0) return 28 + j;                      // r1 DL 8-15
    if (q == 1) return 40 + j;                      // r2 DL 0-7
    if (q == 2) return 48 + j;                      // r2 DL 8-15
    if (j < 4) return 56 + j;                       // r2 DA
    return (j == 4) ? 60 : 61;                      // bias | zero
}

// L2 k-slot (ks,q,j) -> hidden index (sigma bake; verified r9-r15).
__device__ __forceinline__ int hid_of(int ks, int q, int j) {
    return (2 * ks + (j >> 2)) * 16 + q * 4 + (j & 3);
}

// ---- dispatch 1: split bf16 mirror build + fragment bake (verified r10-r15) ----
__global__ __launch_bounds__(256) void build_mirror(
    const f32x4* __restrict__ in, char* __restrict__ m0dl,
    char* __restrict__ mda, f32x4* __restrict__ outF, int n4,
    const float* __restrict__ W1, const float* __restrict__ b1,
    const float* __restrict__ W2, const float* __restrict__ b2,
    char* __restrict__ img)
{
    const int i = blockIdx.x * 256 + threadIdx.x;
    if (i < n4) {
        f32x4 v = in[i];
        u32x2 o; o.x = pack2(v.x, v.y); o.y = pack2(v.z, v.w);
        const int r = i / 5, c = i % 5;          // row, f32x4-within-row
        if (c < 4) {                             // DL piece -> 32B-row mirror
            *(u32x2*)(m0dl + (size_t)r * MDL_ROW + c * 8) = o;
        } else {                                 // DA piece -> static mirror
            *(u32x2*)(mda + (size_t)r * MDA_ROW) = o;
            outF[i] = v;                         // constant DA of output
        }
    }
    if (blockIdx.x == 0) {           // fragment bake (tiny, uniform branch)
        const int t = threadIdx.x, lane = t & 63, g = t >> 6;
        const int l15 = lane & 15, q = lane >> 4;
        for (int f = g; f < NFRAG; f += 4) {
            char* dst = img + (f * 64 + lane) * 16;
            if (f < 16) {                       // B1f[nt][ks]: A[m=nt*16+l15][k]
                const int nt = f >> 1, ks = f & 1, m = nt * 16 + l15;
                unsigned short v[8];
                #pragma unroll
                for (int j = 0; j < 8; j++) {
                    const int ft = feat_of(ks, q, j);
                    float x = (ft < 60) ? TANH_SCALE * W1[ft * 128 + m]
                                        : (ft == 60 ? TANH_SCALE * b1[m] : 0.0f);
                    v[j] = f2bf(x);
                }
                *(u32x4*)dst = *(const u32x4*)v;
            } else if (f < 20) {                // W2f[ks]: sigma-permuted, DT-scaled
                const int ks = f - 16;
                unsigned short v[8];
                #pragma unroll
                for (int j = 0; j < 8; j++) {
                    const int H = hid_of(ks, q, j);
                    v[j] = f2bf(DT_STEP * W2[H * 16 + l15]);
                }
                *(u32x4*)dst = *(const u32x4*)v;
            } else {                            // acc2init: DT*b2[q*4+r]
                f32x4 a = { DT_STEP * b2[q * 4 + 0], DT_STEP * b2[q * 4 + 1],
                            DT_STEP * b2[q * 4 + 2], DT_STEP * b2[q * 4 + 3] };
                *(f32x4*)dst = a;
            }
        }
    }
}

// split-mirror gather (verified r10-r15). q3's 16B loads over-read 8B past
// the DA row; Mda is followed by the frag image, so in-bounds and discarded.
__device__ __forceinline__ void gather3(
    const char* __restrict__ MdlB, const char* __restrict__ MdaB,
    int nx0, int nx1, int nx2,
    int offA, int offB, bool selA, bool selB, bool q3,
    u32x4& A, u32x4& Bv, u32x2& C)
{
    const int rA = selA ? nx1 : nx0;          // q: [r0,r0,r1,-]
    const int rB = selB ? nx2 : nx1;          // q: [r1,r2,r2,-]
    const char* aA = q3 ? (MdaB + (size_t)nx0 * MDA_ROW)
                        : (MdlB + (size_t)rA * MDL_ROW + offA);
    const char* aB = q3 ? (MdaB + (size_t)nx1 * MDA_ROW)
                        : (MdlB + (size_t)rB * MDL_ROW + offB);
    A  = *(const u32x4*)aA;
    Bv = *(const u32x4*)aB;
    u32x2 c = { 0u, 0u };
    if (q3) c = *(const u32x2*)(MdaB + (size_t)nx2 * MDA_ROW);
    C = c;
}

// ---- one Euler step. Verified-optimum structure (r13, 249.5 us total):
// LDS-shared 20.5KB weight image (B1f+W2f), bf16 DL mirror as the ONLY
// inter-step state, sigma-baked in-register layer-2, depth-1 software
// pipeline. Restored exactly after r14 (exact-residency grid) and r15
// (16KB-LDS + nbr-dedup) both regressed. ----
__global__ __launch_bounds__(BLOCK) void neural_step(
    float* __restrict__ Yout,
    const char* __restrict__ Mdl_in, char* __restrict__ Mdl_out,
    const char* __restrict__ Mda,
    const int* __restrict__ nbr, const char* __restrict__ img,
    const int last)
{
    __shared__ __align__(16) char sW[LDS_W_BYTES];   // frags 0..19
    const int t = threadIdx.x, lane = t & 63, w = t >> 6;
    const int l15 = lane & 15, q = lane >> 4;
    const bool q3 = (q == 3);
    const bool selA = (q == 2);                         // A row: r0,r0,r1
    const bool selB = (q == 1) || (q == 2);             // B row: r1,r2,r2
    const int offA = (q == 1) ? 16 : 0;                 // within 32B DL row
    const int offB = (q == 0) || (q == 2) ? 16 : 0;

    const int bk = blockIdx.x;
    const int bB = bk & 7;                 // batch <-> XCD (perf heuristic only)
    const int p0 = (bk >> 3) * (ITERS * PPI) + w * 16 + l15;
    const size_t rowBase = (size_t)bB * NPTS;
    const char* MdlB = Mdl_in  + (size_t)bB * NPTS * MDL_ROW;
    char*       MdoB = Mdl_out + (size_t)bB * NPTS * MDL_ROW;
    const char* MdaB = Mda     + (size_t)bB * NPTS * MDA_ROW;

    // ---- prologue VMEM first: nbr(0,1), gather(0), own(0) in flight ----
    int nx0, nx1, nx2, ny0 = 0, ny1 = 0, ny2 = 0;
    u32x4 gA, gB, nA = {0,0,0,0}, nB = {0,0,0,0};
    u32x2 gC, nC = {0,0};
    u32x2 ownC, ownN = {0u, 0u};
    {
        const int* np = nbr + (size_t)p0 * 3;
        nx0 = np[0]; nx1 = np[1]; nx2 = np[2];
        gather3(MdlB, MdaB, nx0, nx1, nx2, offA, offB, selA, selB, q3,
                gA, gB, gC);
        ownC = *(const u32x2*)(MdlB + (size_t)p0 * MDL_ROW + q * 8);
        const int* np1 = nbr + (size_t)(p0 + PPI) * 3;
        nx0 = np1[0]; nx1 = np1[1]; nx2 = np1[2];
    }

    // ---- stage weight image into LDS (L2-hot source; coalesced) ----
    {
        const u32x4* src = (const u32x4*)img;        // frags 0..19 = 20 KB
        u32x4* dst = (u32x4*)sW;
        #pragma unroll
        for (int k = 0; k < 3; k++) {                // 512 thr x <=3 x 16 B
            const int idx = t + k * 512;
            if (idx < LDS_W_BYTES / 16) dst[idx] = src[idx];
        }
    }
    const f32x4 acc2init = ((const f32x4*)img)[20 * 64 + lane];
    __syncthreads();

    const char* sWl = sW + lane * 16;                // per-lane fragment base

    #pragma unroll
    for (int it = 0; it < ITERS; it++) {
        // ---- prefetch next iter's own row + gather; it+2's nbr ----
        if (it + 1 < ITERS) {
            ownN = *(const u32x2*)(MdlB + (size_t)(p0 + (it + 1) * PPI) * MDL_ROW
                                   + q * 8);
            gather3(MdlB, MdaB, nx0, nx1, nx2, offA, offB, selA, selB, q3,
                    nA, nB, nC);
        }
        if (it + 2 < ITERS) {
            const int* np = nbr + (size_t)(p0 + (it + 2) * PPI) * 3;
            ny0 = np[0]; ny1 = np[1]; ny2 = np[2];
        }

        // assemble permuted B-fragments (q<3: A|B straight; q3: DA pieces +
        // folded bias {1,0,0,0})
        u32x4 u0 = { gA.x, gA.y, q3 ? gB.x : gA.z, q3 ? gB.y : gA.w };
        u32x4 u1 = { q3 ? gC.x : gB.x, q3 ? gC.y : gB.y,
                     q3 ? 0x00003F80u : gB.z, q3 ? 0u : gB.w };
        short8 zb0 = __builtin_bit_cast(short8, u0);
        short8 zb1 = __builtin_bit_cast(short8, u1);

        // ---- layer 1: h in registers; A-operands streamed from LDS ----
        unsigned hx[8], hy[8];
        #pragma unroll
        for (int nt = 0; nt < 8; nt++) {
            short8 a0 = *(const short8*)(sWl + (nt * 2 + 0) * 1024);
            short8 a1 = *(const short8*)(sWl + (nt * 2 + 1) * 1024);
            f32x4 acc = { 0.f, 0.f, 0.f, 0.f };
            acc = __builtin_amdgcn_mfma_f32_16x16x32_bf16(a0, zb0, acc, 0, 0, 0);
            acc = __builtin_amdgcn_mfma_f32_16x16x32_bf16(a1, zb1, acc, 0, 0, 0);
            hx[nt] = pack2(tanh_folded(acc[0]), tanh_folded(acc[1]));
            hy[nt] = pack2(tanh_folded(acc[2]), tanh_folded(acc[3]));
        }

        // ---- layer 2: B-frag direct from registers (sigma bake);
        // A-operand (W2f) streamed from LDS ----
        f32x4 acc2 = acc2init;
        #pragma unroll
        for (int ks = 0; ks < 4; ks++) {
            short8 wf = *(const short8*)(sWl + 16384 + ks * 1024);
            u32x4 hu = { hx[2 * ks], hy[2 * ks], hx[2 * ks + 1], hy[2 * ks + 1] };
            acc2 = __builtin_amdgcn_mfma_f32_16x16x32_bf16(
                wf, __builtin_bit_cast(short8, hu), acc2, 0, 0, 0);
        }

        // ---- epilogue: fp32 update of the lane's 4 DL channels ----
        f32x4 o = unpack4(ownC);
        o.x += acc2[0]; o.y += acc2[1]; o.z += acc2[2]; o.w += acc2[3];
        if (!last) {
            char* mrow = MdoB + (size_t)(p0 + it * PPI) * MDL_ROW;
            u32x2 mw; mw.x = pack2(o.x, o.y); mw.y = pack2(o.z, o.w);
            *(u32x2*)(mrow + q * 8) = mw;
        } else {
            const size_t row = rowBase + (size_t)(p0 + it * PPI);
            __builtin_nontemporal_store(o, (f32x4*)(Yout + row * DTOT) + q);
        }

        // rotate pipeline
        ownC = ownN;
        gA = nA; gB = nB; gC = nC;
        nx0 = ny0; nx1 = ny1; nx2 = ny2;
    }
}

extern "C" void kernel_launch(void* const* d_in, const int* in_sizes, int n_in,
                              void* d_out, int out_size, void* d_ws, size_t ws_size,
                              hipStream_t stream) {
    const float* inputs = (const float*)d_in[0];
    const int*   nbr    = (const int*)  d_in[1];
    const float* W1     = (const float*)d_in[2];
    const float* b1     = (const float*)d_in[3];
    const float* W2     = (const float*)d_in[4];
    const float* b2     = (const float*)d_in[5];
    float* out = (float*)d_out;

    const size_t MDL_BYTES = (size_t)B_DIM * NPTS * MDL_ROW;  // 21.0 MB each
    const size_t MDA_BYTES = (size_t)B_DIM * NPTS * MDA_ROW;  // 5.24 MB
    char* M0 = (char*)d_ws;
    char* M1 = (char*)d_ws + MDL_BYTES;
    char* DA = (char*)d_ws + 2 * MDL_BYTES;
    char* FI = DA + MDA_BYTES;              // frag image (follows DA: q3
                                            // 8B over-reads land here)

    const int n4 = B_DIM * NPTS * DTOT / 4;                 // 3,276,800
    build_mirror<<<n4 / 256, 256, 0, stream>>>(
        (const f32x4*)inputs, M0, DA, (f32x4*)out, n4,
        W1, b1, W2, b2, FI);

    const dim3 grid(GRID), block(BLOCK);
    neural_step<<<grid, block, 0, stream>>>(out, M0, M1, DA, nbr, FI, 0);
    neural_step<<<grid, block, 0, stream>>>(out, M1, M0, DA, nbr, FI, 0);
    neural_step<<<grid, block, 0, stream>>>(out, M0, M1, DA, nbr, FI, 0);
    neural_step<<<grid, block, 0, stream>>>(out, M1, M0, DA, nbr, FI, 1);
}